// Round 6
// baseline (954.898 us; speedup 1.0000x reference)
//
#include <hip/hip_runtime.h>
#include <math.h>

// NoisyTopKRouter: out0 = softmax over top-2 of (x @ route_w^T + route_b) scattered
// into [16384,64]; out1 = top-2 indices (as floats). noise inputs are dead.
//
// R6 = R4's proven K-loop codegen (KR=8, VGPR=64, compiler-interleaved w loads,
// counted vmcnt, no sched_barriers) + 32KB LDS (R5's two-round reduction) +
// __launch_bounds__(512,8) -> 4 blocks/CU, 8 waves/SIMD: hide w-load latency
// with TLP instead of (spill-prone) ILP. R5's spill post-mortem: sched_barrier
// walls forced 16 float4 w-values live -> scratch (1.48 GB of writes).

#define TOKENS 16384
#define EMB    4096
#define NE     64
#define TB     32                 // tokens per block
#define NWAVES 8
#define KQ     (EMB / NWAVES)     // 512 k per wave (split-K)
#define KR     8                  // k per segment
#define NSEG   (KQ / KR)          // 64

#define GLOAD_LDS16(g, l)                                                      \
    __builtin_amdgcn_global_load_lds(                                          \
        (const __attribute__((address_space(1))) void*)(g),                    \
        (__attribute__((address_space(3))) void*)(l), 16, 0, 0)

// wt4[k][le][m] = route_w[le + 16*m][k]  (1 MB in d_ws; lane le reads its 4
// experts {le, le+16, le+32, le+48} for one k as a single float4)
__global__ __launch_bounds__(256) void wt4_prep_kernel(const float* __restrict__ w,
                                                       float* __restrict__ wt4) {
    int idx = blockIdx.x * 256 + threadIdx.x;
    int k   = idx >> 6;
    int col = idx & 63;
    int le  = col >> 2;
    int m   = col & 3;
    wt4[idx] = w[(le + 16 * m) * EMB + k];
}

__global__ __launch_bounds__(512, 8) void router_kernel(const float* __restrict__ x,
                                                        const float* __restrict__ wt4,
                                                        const float* __restrict__ rb,
                                                        float* __restrict__ out) {
    // 32 KB total: [0..4095] = xstage (8 waves x 2 bufs x 256 floats),
    // reused after the K-loop as red[4][32][64] over the whole 8192 floats.
    __shared__ float smem[8192];

    const int tid  = threadIdx.x;
    const int lane = tid & 63;
    const int wq   = __builtin_amdgcn_readfirstlane(tid >> 6);
    const long tok0 = (long)blockIdx.x * TB;

    const int g  = lane >> 4;      // token group: tokens g*8..g*8+7
    const int le = lane & 15;      // expert lane: experts le + 16*m
    const int swz   = g << 4;      // byte XOR for swizzled x reads (bits 4..5)
    const int tbase = g * 256;     // token-group byte base (bits 8..9)

    // staging source (inverse of the read-side XOR swizzle; verified R3/R4):
    // linear buf layout: token t bytes [t*32, t*32+32), half h at +h*16;
    // read addr = (t*32 + h*16) ^ ((t>>3)<<4).
    const int r_  = lane >> 1;
    const int hl  = lane & 1;
    const int t_s = r_ ^ ((r_ >> 4) & 1);
    const int h_s = hl ^ ((r_ >> 3) & 1);
    const float* xsrc = x + (tok0 + t_s) * (long)EMB + wq * KQ + 4 * h_s;

    const float* wsrc = wt4 + (long)(wq * KQ) * NE + le * 4;

    float acc[8][4];
#pragma unroll
    for (int i = 0; i < 8; ++i)
#pragma unroll
        for (int m = 0; m < 4; ++m) acc[i][m] = 0.f;

    float* lds0 = &smem[wq * 512];        // buf 0 (256 floats)
    float* lds1 = &smem[wq * 512 + 256];  // buf 1

    // prologue: stage seg 0
    GLOAD_LDS16(xsrc, lds0);

    auto compute_seg = [&](const float* __restrict__ wseg,
                           const char* __restrict__ xb) {
        float w4a[KR][4];
#pragma unroll
        for (int k = 0; k < KR; ++k)
            *reinterpret_cast<float4*>(&w4a[k][0]) =
                *reinterpret_cast<const float4*>(wseg + k * NE);
#pragma unroll
        for (int i = 0; i < 8; ++i) {
            const float4 xa = *reinterpret_cast<const float4*>(xb + ((tbase + i * 32 + 0)  ^ swz));
            const float4 xc = *reinterpret_cast<const float4*>(xb + ((tbase + i * 32 + 16) ^ swz));
#pragma unroll
            for (int m = 0; m < 4; ++m) {
                float a = acc[i][m];
                a = fmaf(xa.x, w4a[0][m], a);
                a = fmaf(xa.y, w4a[1][m], a);
                a = fmaf(xa.z, w4a[2][m], a);
                a = fmaf(xa.w, w4a[3][m], a);
                a = fmaf(xc.x, w4a[4][m], a);
                a = fmaf(xc.y, w4a[5][m], a);
                a = fmaf(xc.z, w4a[6][m], a);
                a = fmaf(xc.w, w4a[7][m], a);
                acc[i][m] = a;
            }
        }
    };

    for (int s = 0; s < NSEG - 1; ++s) {
        const int b = s & 1;
        // stage next seg into the other buffer (stays in flight during compute)
        GLOAD_LDS16(xsrc + (s + 1) * KR, (b ? lds0 : lds1));
        // wait until at most the newest stage is outstanding -> stage(s) done
        asm volatile("s_waitcnt vmcnt(1)" ::: "memory");
        compute_seg(wsrc + (long)s * KR * NE,
                    (const char*)(b ? lds1 : lds0));
    }
    {   // final segment
        const int b = (NSEG - 1) & 1;
        asm volatile("s_waitcnt vmcnt(0)" ::: "memory");
        compute_seg(wsrc + (long)(NSEG - 1) * KR * NE,
                    (const char*)(b ? lds1 : lds0));
    }

    // ---- two-round cross-wave reduction (aliases xstage; barrier-separated) ----
    __syncthreads();
    if (wq >= 4) {   // round A: waves 4..7 store partials
#pragma unroll
        for (int i = 0; i < 8; ++i)
#pragma unroll
            for (int m = 0; m < 4; ++m)
                smem[((wq & 3) * 32 + g * 8 + i) * 64 + le + 16 * m] = acc[i][m];
    }
    __syncthreads();
    if (wq < 4) {    // round B: waves 0..3 accumulate into the same cells
#pragma unroll
        for (int i = 0; i < 8; ++i)
#pragma unroll
            for (int m = 0; m < 4; ++m) {
                const int idx = ((wq & 3) * 32 + g * 8 + i) * 64 + le + 16 * m;
                smem[idx] += acc[i][m];
            }
    }
    __syncthreads();
    // final 4-way sum + bias -> smem[t*64+e] (each thread RMWs only its own cells)
    {
        const int t  = tid >> 4;          // 0..31
        const int e0 = (tid & 15) * 4;
        float4 sum = *reinterpret_cast<const float4*>(rb + e0);
#pragma unroll
        for (int r = 0; r < 4; ++r) {
            const float4 p = *reinterpret_cast<const float4*>(&smem[(r * 32 + t) * 64 + e0]);
            sum.x += p.x; sum.y += p.y; sum.z += p.z; sum.w += p.w;
        }
        *reinterpret_cast<float4*>(&smem[t * 64 + e0]) = sum;
    }
    __syncthreads();

    // top-2 (jax tie rule: ascending scan, strict >) + 2-way softmax
    if (tid < TB) {
        const int t = tid;
        float m1 = -INFINITY, m2 = -INFINITY;
        int i1 = 0, i2 = 0;
        for (int e = 0; e < NE; ++e) {
            float v = smem[t * 64 + e];
            if (v > m1)      { m2 = m1; i2 = i1; m1 = v; i1 = e; }
            else if (v > m2) { m2 = v;  i2 = e; }
        }
        const float ed = expf(m2 - m1);
        const float p1 = 1.f / (1.f + ed);
        smem[2048 + t]      = p1;
        smem[2048 + 32 + t] = 1.f - p1;
        smem[2048 + 64 + t] = (float)i1;
        smem[2048 + 96 + t] = (float)i2;
    }
    __syncthreads();

    // write router_output rows (every element, zeros included), float4 coalesced
    {
        const int t  = tid >> 4;
        const int e0 = (tid & 15) * 4;
        const int i1 = (int)smem[2048 + 64 + t];
        const int i2 = (int)smem[2048 + 96 + t];
        const float p1 = smem[2048 + t];
        const float p2 = smem[2048 + 32 + t];
        float v[4];
#pragma unroll
        for (int j = 0; j < 4; ++j) {
            const int e = e0 + j;
            v[j] = (e == i1) ? p1 : ((e == i2) ? p2 : 0.f);
        }
        *reinterpret_cast<float4*>(out + (tok0 + t) * NE + e0) =
            make_float4(v[0], v[1], v[2], v[3]);
    }
    if (tid < TB) {
        float* idxo = out + (long)TOKENS * NE + (tok0 + tid) * 2;
        idxo[0] = smem[2048 + 64 + tid];
        idxo[1] = smem[2048 + 96 + tid];
    }
}

extern "C" void kernel_launch(void* const* d_in, const int* in_sizes, int n_in,
                              void* d_out, int out_size, void* d_ws, size_t ws_size,
                              hipStream_t stream) {
    const float* x       = (const float*)d_in[0];
    const float* route_w = (const float*)d_in[2];
    const float* route_b = (const float*)d_in[3];
    float* wt4 = (float*)d_ws;          // 1 MB scratch
    float* out = (float*)d_out;

    hipLaunchKernelGGL(wt4_prep_kernel, dim3((EMB * NE) / 256), dim3(256), 0, stream,
                       route_w, wt4);
    hipLaunchKernelGGL(router_kernel, dim3(TOKENS / TB), dim3(512), 0, stream,
                       x, wt4, route_b, out);
}

// Round 7
// 158.619 us; speedup vs baseline: 6.0201x; 6.0201x over previous
//
#include <hip/hip_runtime.h>
#include <math.h>

// NoisyTopKRouter: out0 = softmax over top-2 of (x @ route_w^T + route_b) scattered
// into [16384,64]; out1 = top-2 indices (as floats). noise inputs are dead.
//
// R7 = R6 with __launch_bounds__(512,4) restored.
// Evidence: identical K-loop compiles to 64 VGPR/no-spill under (512,4) [R4],
// but 32 VGPR/full-spill under (512,8) [R6: 2.4 GB scratch writes]. Occupancy
// is set at runtime by actual VGPR(64)+LDS(32KB) -> 4 blocks/CU, 8 waves/SIMD;
// the launch-bounds promise only throttles the register allocator.

#define TOKENS 16384
#define EMB    4096
#define NE     64
#define TB     32                 // tokens per block
#define NWAVES 8
#define KQ     (EMB / NWAVES)     // 512 k per wave (split-K)
#define KR     8                  // k per segment
#define NSEG   (KQ / KR)          // 64

#define GLOAD_LDS16(g, l)                                                      \
    __builtin_amdgcn_global_load_lds(                                          \
        (const __attribute__((address_space(1))) void*)(g),                    \
        (__attribute__((address_space(3))) void*)(l), 16, 0, 0)

// wt4[k][le][m] = route_w[le + 16*m][k]  (1 MB in d_ws; lane le reads its 4
// experts {le, le+16, le+32, le+48} for one k as a single float4)
__global__ __launch_bounds__(256) void wt4_prep_kernel(const float* __restrict__ w,
                                                       float* __restrict__ wt4) {
    int idx = blockIdx.x * 256 + threadIdx.x;
    int k   = idx >> 6;
    int col = idx & 63;
    int le  = col >> 2;
    int m   = col & 3;
    wt4[idx] = w[(le + 16 * m) * EMB + k];
}

__global__ __launch_bounds__(512, 4) void router_kernel(const float* __restrict__ x,
                                                        const float* __restrict__ wt4,
                                                        const float* __restrict__ rb,
                                                        float* __restrict__ out) {
    // 32 KB total: [0..4095] = xstage (8 waves x 2 bufs x 256 floats),
    // reused after the K-loop as red[4][32][64] over the whole 8192 floats.
    __shared__ float smem[8192];

    const int tid  = threadIdx.x;
    const int lane = tid & 63;
    const int wq   = __builtin_amdgcn_readfirstlane(tid >> 6);
    const long tok0 = (long)blockIdx.x * TB;

    const int g  = lane >> 4;      // token group: tokens g*8..g*8+7
    const int le = lane & 15;      // expert lane: experts le + 16*m
    const int swz   = g << 4;      // byte XOR for swizzled x reads (bits 4..5)
    const int tbase = g * 256;     // token-group byte base (bits 8..9)

    // staging source (inverse of the read-side XOR swizzle; verified R3/R4):
    // linear buf layout: token t bytes [t*32, t*32+32), half h at +h*16;
    // read addr = (t*32 + h*16) ^ ((t>>3)<<4).
    const int r_  = lane >> 1;
    const int hl  = lane & 1;
    const int t_s = r_ ^ ((r_ >> 4) & 1);
    const int h_s = hl ^ ((r_ >> 3) & 1);
    const float* xsrc = x + (tok0 + t_s) * (long)EMB + wq * KQ + 4 * h_s;

    const float* wsrc = wt4 + (long)(wq * KQ) * NE + le * 4;

    float acc[8][4];
#pragma unroll
    for (int i = 0; i < 8; ++i)
#pragma unroll
        for (int m = 0; m < 4; ++m) acc[i][m] = 0.f;

    float* lds0 = &smem[wq * 512];        // buf 0 (256 floats)
    float* lds1 = &smem[wq * 512 + 256];  // buf 1

    // prologue: stage seg 0
    GLOAD_LDS16(xsrc, lds0);

    auto compute_seg = [&](const float* __restrict__ wseg,
                           const char* __restrict__ xb) {
        float w4a[KR][4];
#pragma unroll
        for (int k = 0; k < KR; ++k)
            *reinterpret_cast<float4*>(&w4a[k][0]) =
                *reinterpret_cast<const float4*>(wseg + k * NE);
#pragma unroll
        for (int i = 0; i < 8; ++i) {
            const float4 xa = *reinterpret_cast<const float4*>(xb + ((tbase + i * 32 + 0)  ^ swz));
            const float4 xc = *reinterpret_cast<const float4*>(xb + ((tbase + i * 32 + 16) ^ swz));
#pragma unroll
            for (int m = 0; m < 4; ++m) {
                float a = acc[i][m];
                a = fmaf(xa.x, w4a[0][m], a);
                a = fmaf(xa.y, w4a[1][m], a);
                a = fmaf(xa.z, w4a[2][m], a);
                a = fmaf(xa.w, w4a[3][m], a);
                a = fmaf(xc.x, w4a[4][m], a);
                a = fmaf(xc.y, w4a[5][m], a);
                a = fmaf(xc.z, w4a[6][m], a);
                a = fmaf(xc.w, w4a[7][m], a);
                acc[i][m] = a;
            }
        }
    };

    for (int s = 0; s < NSEG - 1; ++s) {
        const int b = s & 1;
        // stage next seg into the other buffer (stays in flight during compute)
        GLOAD_LDS16(xsrc + (s + 1) * KR, (b ? lds0 : lds1));
        // wait until at most the newest stage is outstanding -> stage(s) done
        asm volatile("s_waitcnt vmcnt(1)" ::: "memory");
        compute_seg(wsrc + (long)s * KR * NE,
                    (const char*)(b ? lds1 : lds0));
    }
    {   // final segment
        const int b = (NSEG - 1) & 1;
        asm volatile("s_waitcnt vmcnt(0)" ::: "memory");
        compute_seg(wsrc + (long)(NSEG - 1) * KR * NE,
                    (const char*)(b ? lds1 : lds0));
    }

    // ---- two-round cross-wave reduction (aliases xstage; barrier-separated) ----
    __syncthreads();
    if (wq >= 4) {   // round A: waves 4..7 store partials
#pragma unroll
        for (int i = 0; i < 8; ++i)
#pragma unroll
            for (int m = 0; m < 4; ++m)
                smem[((wq & 3) * 32 + g * 8 + i) * 64 + le + 16 * m] = acc[i][m];
    }
    __syncthreads();
    if (wq < 4) {    // round B: waves 0..3 accumulate into the same cells
#pragma unroll
        for (int i = 0; i < 8; ++i)
#pragma unroll
            for (int m = 0; m < 4; ++m) {
                const int idx = ((wq & 3) * 32 + g * 8 + i) * 64 + le + 16 * m;
                smem[idx] += acc[i][m];
            }
    }
    __syncthreads();
    // final 4-way sum + bias -> smem[t*64+e] (each thread RMWs only its own cells)
    {
        const int t  = tid >> 4;          // 0..31
        const int e0 = (tid & 15) * 4;
        float4 sum = *reinterpret_cast<const float4*>(rb + e0);
#pragma unroll
        for (int r = 0; r < 4; ++r) {
            const float4 p = *reinterpret_cast<const float4*>(&smem[(r * 32 + t) * 64 + e0]);
            sum.x += p.x; sum.y += p.y; sum.z += p.z; sum.w += p.w;
        }
        *reinterpret_cast<float4*>(&smem[t * 64 + e0]) = sum;
    }
    __syncthreads();

    // top-2 (jax tie rule: ascending scan, strict >) + 2-way softmax
    if (tid < TB) {
        const int t = tid;
        float m1 = -INFINITY, m2 = -INFINITY;
        int i1 = 0, i2 = 0;
        for (int e = 0; e < NE; ++e) {
            float v = smem[t * 64 + e];
            if (v > m1)      { m2 = m1; i2 = i1; m1 = v; i1 = e; }
            else if (v > m2) { m2 = v;  i2 = e; }
        }
        const float ed = expf(m2 - m1);
        const float p1 = 1.f / (1.f + ed);
        smem[2048 + t]      = p1;
        smem[2048 + 32 + t] = 1.f - p1;
        smem[2048 + 64 + t] = (float)i1;
        smem[2048 + 96 + t] = (float)i2;
    }
    __syncthreads();

    // write router_output rows (every element, zeros included), float4 coalesced
    {
        const int t  = tid >> 4;
        const int e0 = (tid & 15) * 4;
        const int i1 = (int)smem[2048 + 64 + t];
        const int i2 = (int)smem[2048 + 96 + t];
        const float p1 = smem[2048 + t];
        const float p2 = smem[2048 + 32 + t];
        float v[4];
#pragma unroll
        for (int j = 0; j < 4; ++j) {
            const int e = e0 + j;
            v[j] = (e == i1) ? p1 : ((e == i2) ? p2 : 0.f);
        }
        *reinterpret_cast<float4*>(out + (tok0 + t) * NE + e0) =
            make_float4(v[0], v[1], v[2], v[3]);
    }
    if (tid < TB) {
        float* idxo = out + (long)TOKENS * NE + (tok0 + tid) * 2;
        idxo[0] = smem[2048 + 64 + tid];
        idxo[1] = smem[2048 + 96 + tid];
    }
}

extern "C" void kernel_launch(void* const* d_in, const int* in_sizes, int n_in,
                              void* d_out, int out_size, void* d_ws, size_t ws_size,
                              hipStream_t stream) {
    const float* x       = (const float*)d_in[0];
    const float* route_w = (const float*)d_in[2];
    const float* route_b = (const float*)d_in[3];
    float* wt4 = (float*)d_ws;          // 1 MB scratch
    float* out = (float*)d_out;

    hipLaunchKernelGGL(wt4_prep_kernel, dim3((EMB * NE) / 256), dim3(256), 0, stream,
                       route_w, wt4);
    hipLaunchKernelGGL(router_kernel, dim3(TOKENS / TB), dim3(512), 0, stream,
                       x, wt4, route_b, out);
}